// Round 9
// baseline (237.090 us; speedup 1.0000x reference)
//
#include <hip/hip_runtime.h>
#include <stdint.h>

// out[b,n] = sum_{c,hw} x[b,c,hw]*W_s[n,hw]*W_d[n,c] + W_b[n]
// GEMM: A = x (M=8192, K=3136), B = W_s (N=1024, K=3136), fused c-contraction.
// R8: R5 core (256x128 tile, 8 waves, BK=64, split-K x2, 2 blocks/CU) +
//     A-conversion FUSED into staging: global fp32 loads -> bf16 pack in reg
//     -> ds_write_b128 (same XOR-swizzle layout). Kills the 154 MB x-convert
//     round-trip (~27 us) by riding gemm's 87% idle HBM. B stays DMA'd from a
//     small W_s bf16 pre-convert (6.4 MB in ws).

#define K_DIM 3136
#define N_DIM 1024
#define C_DIM 256
#define B_DIM 32
#define M_DIM 8192
#define WS_ELEMS (N_DIM * K_DIM)  // 3211264

typedef __attribute__((ext_vector_type(8))) short short8v;  // 8 bf16
typedef __attribute__((ext_vector_type(4))) float f32x4;
typedef __attribute__((ext_vector_type(4))) unsigned int uint4v;

// round-to-nearest-even fp32 -> bf16 (W_s pre-convert)
__device__ __forceinline__ short f2bf(float f) {
  union { float f; unsigned u; } v; v.f = f;
  unsigned r = v.u + 0x7FFFu + ((v.u >> 16) & 1u);
  return (short)(r >> 16);
}

// pack two fp32 -> two bf16 (round-half-up; same +-half-ulp error as RNE)
__device__ __forceinline__ unsigned pk2bf(float a, float b) {
  unsigned ua = __float_as_uint(a) + 0x8000u;
  unsigned ub = __float_as_uint(b) + 0x8000u;
  return (ua >> 16) | (ub & 0xFFFF0000u);
}

// 16B-per-lane async global->LDS. LDS dest = wave-uniform base + lane*16.
__device__ __forceinline__ void async16(const void* g, void* l) {
  __builtin_amdgcn_global_load_lds(
      (const __attribute__((address_space(1))) unsigned int*)g,
      (__attribute__((address_space(3))) unsigned int*)l, 16, 0, 0);
}

// fp32 -> bf16 for W_s only (x handled inside gemm), plus bias into out.
#define WSBLK (WS_ELEMS / 2048)  // 1568
__global__ __launch_bounds__(256) void convert_ws_bias(
    const float* __restrict__ Ws, const float* __restrict__ Wb,
    short* __restrict__ dst, float* __restrict__ out) {
  int bid = blockIdx.x;
  if (bid >= WSBLK) {  // bias: 32768 out elems / 256 = 128 blocks
    int i = (bid - WSBLK) * 256 + threadIdx.x;
    out[i] = Wb[i & (N_DIM - 1)];
    return;
  }
  size_t i = (size_t)bid * 2048 + threadIdx.x * 8;
  f32x4 v0 = __builtin_nontemporal_load((const f32x4*)(Ws + i));
  f32x4 v1 = __builtin_nontemporal_load((const f32x4*)(Ws + i) + 1);
  short8v s;
  s[0] = f2bf(v0.x); s[1] = f2bf(v0.y); s[2] = f2bf(v0.z); s[3] = f2bf(v0.w);
  s[4] = f2bf(v1.x); s[5] = f2bf(v1.y); s[6] = f2bf(v1.z); s[7] = f2bf(v1.w);
  *(short8v*)(dst + i) = s;
}

// LDS: rows of 8 chunks (chunk = 8 bf16 = 16 B), unpadded. slot(row, cs)
// holds global chunk cs ^ (row&7); frag reads XOR back -> conflict-free
// (verified R1..R7: SQ_LDS_BANK_CONFLICT = 0). A written by threads (packed
// from fp32), B written by DMA.
__global__ __launch_bounds__(512, 4) void gemm_fused(
    const float* __restrict__ x, const short* __restrict__ Bbf,
    const float* __restrict__ Wd, float* __restrict__ out) {
  __shared__ __align__(16) short As[256 * 64];  // 32 KB
  __shared__ __align__(16) short Bs[128 * 64];  // 16 KB

  const int bid = blockIdx.x;
  const int mt = bid & 31;          // bid%8 == mt%8 -> A-tile pinned to XCD
  const int nt = (bid >> 5) & 7;
  const int z = bid >> 8;           // K-split half: 49 = 25 + 24
  const int kt0 = z * 25;
  const int ktn = z ? 24 : 25;

  const int t = threadIdx.x;
  const int lane = t & 63;
  const int wv = t >> 6;            // 0..7
  const int r = lane & 15;
  const int q = lane >> 4;
  const int wm = wv >> 1, wn = wv & 1;  // 4x2 wave grid over 256x128 tile

  // B staging (DMA): lane -> (rr, k8); wave covers rows [wv*16, +16), p=0..1.
  const int rr = lane >> 3;
  const int k8 = (lane & 7) ^ rr;
  const short* Bw = Bbf + (size_t)(nt * 128 + wv * 16 + rr) * K_DIM + k8 * 8 + kt0 * 64;
  char* BsB = (char*)Bs + wv * 2048;

  // A staging (fp32 -> pack): lane -> (rr8 = row-in-8-group, c8 = chunk).
  // Pair w covers rows [wv*32 + w*8, +8); lane loads 8 floats = chunk c8.
  const int rr8 = lane >> 3;
  const int c8 = lane & 7;
  const int slotA = c8 ^ rr8;       // row&7 == rr8 for all w (w*8 stride)
  const float* Aw =
      x + (size_t)(mt * 256 + wv * 32 + rr8) * K_DIM + kt0 * 64 + c8 * 8;
  short* AsW = As + (wv * 32 + rr8) * 64 + slotA * 8;

  f32x4 acc[4][4];
#pragma unroll
  for (int i = 0; i < 4; ++i)
#pragma unroll
    for (int j = 0; j < 4; ++j) acc[i][j] = (f32x4)0.0f;

  for (int kt = 0; kt < ktn; ++kt) {
    __syncthreads();  // prev iteration's LDS reads done
    // B tile via async DMA
#pragma unroll
    for (int p = 0; p < 2; ++p)
      async16(Bw + (size_t)p * 8 * K_DIM + kt * 64, BsB + p * 1024);
    // A tile: fp32 loads -> bf16 pack -> LDS
#pragma unroll
    for (int w = 0; w < 4; ++w) {
      const float* g = Aw + (size_t)w * 8 * K_DIM + kt * 64;
      f32x4 va = *(const f32x4*)g;
      f32x4 vb = *(const f32x4*)(g + 4);
      uint4v u;
      u.x = pk2bf(va.x, va.y);
      u.y = pk2bf(va.z, va.w);
      u.z = pk2bf(vb.x, vb.y);
      u.w = pk2bf(vb.z, vb.w);
      *(uint4v*)(AsW + (size_t)w * 8 * 64) = u;
    }
    __syncthreads();  // drains vmcnt(0) (B-DMA) + lgkm (A ds_writes)

#pragma unroll
    for (int ks = 0; ks < 2; ++ks) {
      const int xo = ((ks * 4 + q) ^ (r & 7)) * 16;
      short8v a[4], b[4];
#pragma unroll
      for (int i = 0; i < 4; ++i)
        a[i] = *(const short8v*)((const char*)As + (64 * wm + 16 * i + r) * 128 + xo);
#pragma unroll
      for (int j = 0; j < 4; ++j)
        b[j] = *(const short8v*)((const char*)Bs + (64 * wn + 16 * j + r) * 128 + xo);
#pragma unroll
      for (int i = 0; i < 4; ++i)
#pragma unroll
        for (int j = 0; j < 4; ++j)
          acc[i][j] = __builtin_amdgcn_mfma_f32_16x16x32_bf16(a[i], b[j],
                                                              acc[i][j], 0, 0, 0);
    }
  }

  // epilogue: out[mt, n] += sum_c acc * W_d[n, c]; A-tile = image mt, c = row.
  // C/D frag layout: col = lane&15 (n), row = q*4 + reg (c).
#pragma unroll
  for (int j = 0; j < 4; ++j) {
    const int n_g = nt * 128 + 64 * wn + 16 * j + r;
    float p = 0.0f;
#pragma unroll
    for (int i = 0; i < 4; ++i) {
      const int c_l = 64 * wm + 16 * i + 4 * q;
      const float4 wd = *(const float4*)(Wd + (size_t)n_g * C_DIM + c_l);
      p += acc[i][j].x * wd.x + acc[i][j].y * wd.y + acc[i][j].z * wd.z +
           acc[i][j].w * wd.w;
    }
    p += __shfl_xor(p, 16, 64);
    p += __shfl_xor(p, 32, 64);
    if (q == 0) atomicAdd(&out[(size_t)mt * N_DIM + n_g], p);
  }
}

extern "C" void kernel_launch(void* const* d_in, const int* in_sizes, int n_in,
                              void* d_out, int out_size, void* d_ws, size_t ws_size,
                              hipStream_t stream) {
  const float* x = (const float*)d_in[0];
  const float* Ws = (const float*)d_in[1];
  const float* Wd = (const float*)d_in[2];
  const float* Wb = (const float*)d_in[3];
  float* out = (float*)d_out;
  short* wsbf = (short*)d_ws;  // [WS_ELEMS] bf16 W_s only

  convert_ws_bias<<<dim3(WSBLK + 128), dim3(256), 0, stream>>>(Ws, Wb, wsbf, out);
  gemm_fused<<<dim3(32 * 8 * 2), dim3(512), 0, stream>>>(x, wsbf, Wd, out);
}